// Round 1
// baseline (651.983 us; speedup 1.0000x reference)
//
#include <hip/hip_runtime.h>

typedef unsigned short u16;
typedef unsigned int u32;
typedef unsigned long long u64;
typedef __bf16 bf16x8 __attribute__((ext_vector_type(8)));
typedef float f32x4 __attribute__((ext_vector_type(4)));
typedef u32 u32x4 __attribute__((ext_vector_type(4)));

#define DEV static __device__ __forceinline__

constexpr int B_ = 2, L_ = 2048, H_ = 2048;
constexpr int NH_ = 16, HD_ = 128, RD_ = 64;
constexpr int QR_ = 768, KVR_ = 512;
constexpr int BL_ = B_ * L_;          // 4096 tokens
constexpr int QKD_ = HD_ + RD_;       // 192
constexpr int QKS_ = NH_ * QKD_;      // 3072
constexpr int NHHD_ = NH_ * HD_;      // 2048

DEV u16 f2bf(float f) {
    u32 u = __builtin_bit_cast(u32, f);
    u32 r = (u + 0x7fffu + ((u >> 16) & 1u)) >> 16;
    return (u16)r;
}
DEV float bf2f(u16 h) {
    u32 u = ((u32)h) << 16;
    return __builtin_bit_cast(float, u);
}
DEV bf16x8 ld8(const u16* p) { return __builtin_bit_cast(bf16x8, *(const u32x4*)p); }
DEV f32x4 mfma16(bf16x8 a, bf16x8 b, f32x4 c) {
    return __builtin_amdgcn_mfma_f32_16x16x32_bf16(a, b, c, 0, 0, 0);
}

// ---------------- elementwise cast: f32 -> bf16, 4 elems/thread ----------------
__global__ __launch_bounds__(256) void cast_bf16_kernel(const float* __restrict__ src,
                                                        u16* __restrict__ dst, int n4) {
    int i = blockIdx.x * 256 + threadIdx.x;
    if (i >= n4) return;
    float4 v = ((const float4*)src)[i];
    u64 pk = (u64)f2bf(v.x) | ((u64)f2bf(v.y) << 16) | ((u64)f2bf(v.z) << 32) | ((u64)f2bf(v.w) << 48);
    ((u64*)dst)[i] = pk;
}

// ------------- cast + transpose: src (K x N) f32  ->  dst (dstN x K) bf16, zero-pad rows >= N -------------
__global__ __launch_bounds__(256) void cast_transpose(const float* __restrict__ src, u16* __restrict__ dst,
                                                      int K, int N, int dstN) {
    __shared__ float tile[32][33];
    int n0 = blockIdx.x * 32, k0 = blockIdx.y * 32;
    int tx = threadIdx.x & 31, ty = threadIdx.x >> 5;  // 32 x 8
#pragma unroll
    for (int i = 0; i < 4; ++i) {
        int kk = ty + i * 8;
        int n = n0 + tx;
        tile[kk][tx] = (n < N) ? src[(size_t)(k0 + kk) * N + n] : 0.f;
    }
    __syncthreads();
#pragma unroll
    for (int i = 0; i < 4; ++i) {
        int nn = ty + i * 8;
        dst[(size_t)(n0 + nn) * K + k0 + tx] = f2bf(tile[tx][nn]);
    }
}

// ---------------- GEMM: C(MxN) = A(MxK,row) * Bt(NxK,row)^T, bf16 in, bf16/f32 out ----------------
// 128x128 tile, 4 waves (2x2), each wave 64x64 = 4x4 of 16x16x32 MFMA, BK=32.
// LDS rows padded to 40 elems (80 B) -> 2-way (free) bank pattern on ds_read_b128.
template <int OUTF32>
__global__ __launch_bounds__(256, 2) void gemm_bt(const u16* __restrict__ A, const u16* __restrict__ Bt,
                                                  void* __restrict__ Cv, int M, int N, int K) {
    __shared__ u16 As[128 * 40];
    __shared__ u16 Bs[128 * 40];
    const int tid = threadIdx.x;
    const int l = tid & 63, w = tid >> 6;
    const int l15 = l & 15, g = l >> 4;
    const int wr = w >> 1, wc = w & 1;
    const int bm = blockIdx.y * 128, bn = blockIdx.x * 128;
    const int r0 = tid >> 2, c0 = tid & 3;

    const f32x4 zero = {0.f, 0.f, 0.f, 0.f};
    f32x4 acc[4][4];
#pragma unroll
    for (int m = 0; m < 4; ++m)
#pragma unroll
        for (int n = 0; n < 4; ++n) acc[m][n] = zero;

    const u16* aptr0 = A + (size_t)(bm + r0) * K + c0 * 8;
    const u16* aptr1 = A + (size_t)(bm + 64 + r0) * K + c0 * 8;
    const u16* bptr0 = Bt + (size_t)(bn + r0) * K + c0 * 8;
    const u16* bptr1 = Bt + (size_t)(bn + 64 + r0) * K + c0 * 8;

    u32x4 ra0 = *(const u32x4*)aptr0, ra1 = *(const u32x4*)aptr1;
    u32x4 rb0 = *(const u32x4*)bptr0, rb1 = *(const u32x4*)bptr1;

    const int nK = K / 32;
    for (int kt = 0; kt < nK; ++kt) {
        __syncthreads();
        *(u32x4*)((char*)As + r0 * 80 + c0 * 16) = ra0;
        *(u32x4*)((char*)As + (64 + r0) * 80 + c0 * 16) = ra1;
        *(u32x4*)((char*)Bs + r0 * 80 + c0 * 16) = rb0;
        *(u32x4*)((char*)Bs + (64 + r0) * 80 + c0 * 16) = rb1;
        __syncthreads();
        if (kt + 1 < nK) {
            int ko = (kt + 1) * 32;
            ra0 = *(const u32x4*)(aptr0 + ko);
            ra1 = *(const u32x4*)(aptr1 + ko);
            rb0 = *(const u32x4*)(bptr0 + ko);
            rb1 = *(const u32x4*)(bptr1 + ko);
        }
        bf16x8 af[4], bfr[4];
#pragma unroll
        for (int m = 0; m < 4; ++m)
            af[m] = ld8((const u16*)((const char*)As + (wr * 64 + m * 16 + l15) * 80 + g * 16));
#pragma unroll
        for (int n = 0; n < 4; ++n)
            bfr[n] = ld8((const u16*)((const char*)Bs + (wc * 64 + n * 16 + l15) * 80 + g * 16));
#pragma unroll
        for (int m = 0; m < 4; ++m)
#pragma unroll
            for (int n = 0; n < 4; ++n) acc[m][n] = mfma16(af[m], bfr[n], acc[m][n]);
    }
#pragma unroll
    for (int m = 0; m < 4; ++m)
#pragma unroll
        for (int n = 0; n < 4; ++n)
#pragma unroll
            for (int r = 0; r < 4; ++r) {
                int row = bm + wr * 64 + m * 16 + g * 4 + r;
                int col = bn + wc * 64 + n * 16 + l15;
                if (OUTF32)
                    ((float*)Cv)[(size_t)row * N + col] = acc[m][n][r];
                else
                    ((u16*)Cv)[(size_t)row * N + col] = f2bf(acc[m][n][r]);
            }
}

// ------------- pack: src [BL][2048] -> dst [BL][3072] at h*192 + d (d<128) -------------
__global__ __launch_bounds__(256) void pack_content(const u16* __restrict__ src, u16* __restrict__ dst) {
    size_t i = (size_t)blockIdx.x * 256 + threadIdx.x;  // BL*2048/8
    int token = (int)(i >> 8), c = (int)(i & 255);
    int h = c >> 4, d8 = c & 15;
    u32x4 v = *(const u32x4*)(src + (size_t)token * NHHD_ + c * 8);
    *(u32x4*)(dst + (size_t)token * QKS_ + h * QKD_ + d8 * 8) = v;
}

// ------------- RoPE on q_rope (BL x NH*64), write into q at h*192+128+i -------------
__global__ __launch_bounds__(256) void rope_q_kernel(const u16* __restrict__ src, u16* __restrict__ dst) {
    int idx = blockIdx.x * 256 + threadIdx.x;  // BL*NH*32
    int token = idx >> 9;
    int r = idx & 511;
    int h = r >> 5, i = r & 31;
    int pos = token & (L_ - 1);
    float ang = (float)pos * powf(10000.f, -(float)i * (1.f / 32.f));
    float c = cosf(ang), s = sinf(ang);
    float x1 = bf2f(src[(size_t)token * (NH_ * RD_) + h * RD_ + i]);
    float x2 = bf2f(src[(size_t)token * (NH_ * RD_) + h * RD_ + i + 32]);
    u16* base = dst + (size_t)token * QKS_ + h * QKD_ + HD_;
    base[i] = f2bf(x1 * c - x2 * s);
    base[i + 32] = f2bf(x2 * c + x1 * s);
}

// ------------- RoPE on k_rope (BL x 128 padded, 64 valid) + broadcast to all heads of k -------------
__global__ __launch_bounds__(256) void rope_k_kernel(const u16* __restrict__ src, u16* __restrict__ dst) {
    int idx = blockIdx.x * 256 + threadIdx.x;  // BL*32
    int token = idx >> 5, i = idx & 31;
    int pos = token & (L_ - 1);
    float ang = (float)pos * powf(10000.f, -(float)i * (1.f / 32.f));
    float c = cosf(ang), s = sinf(ang);
    float x1 = bf2f(src[(size_t)token * 128 + i]);
    float x2 = bf2f(src[(size_t)token * 128 + i + 32]);
    u16 o1 = f2bf(x1 * c - x2 * s);
    u16 o2 = f2bf(x2 * c + x1 * s);
    u16* base = dst + (size_t)token * QKS_ + HD_;
#pragma unroll
    for (int h = 0; h < NH_; ++h) {
        base[h * QKD_ + i] = o1;
        base[h * QKD_ + i + 32] = o2;
    }
}

// ------------- transpose v [BL][2048] -> vt [(b*2048+col)][L] -------------
__global__ __launch_bounds__(256) void transpose_v(const u16* __restrict__ v, u16* __restrict__ vt) {
    __shared__ u16 tile[64][72];
    int cb = blockIdx.x * 64, lb = blockIdx.y * 64, b = blockIdx.z;
    int tid = threadIdx.x;
    int tr = tid >> 3, tc = (tid & 7) * 8;
#pragma unroll
    for (int i = 0; i < 2; ++i) {
        int row = tr + i * 32;
        u32x4 d = *(const u32x4*)(v + (size_t)(b * L_ + lb + row) * NHHD_ + cb + tc);
        *(u32x4*)&tile[row][tc] = d;
    }
    __syncthreads();
#pragma unroll
    for (int i = 0; i < 2; ++i) {
        int col = tr + i * 32;
        u16 tmp[8];
#pragma unroll
        for (int j = 0; j < 8; ++j) tmp[j] = tile[tc + j][col];
        *(u32x4*)(vt + (size_t)(b * NHHD_ + cb + col) * L_ + lb + tc) = *(u32x4*)tmp;
    }
}

// ------------- causal flash attention -------------
// grid (L/64, NH, B); 256 threads = 4 waves, wave w owns q rows q0+16w..+15.
// K tile [64][192] in LDS (row stride 400B), Vt tile [128][64] (stride 144B),
// P per wave [16][64] (stride 144B). Online softmax per row, 16-lane shfl reduce.
__global__ __launch_bounds__(256, 2) void flash_attn(const u16* __restrict__ q, const u16* __restrict__ k,
                                                     const u16* __restrict__ vt, u16* __restrict__ attn_o) {
    __shared__ __align__(16) char smem[25600 + 18432 + 4 * 2304];
    char* Ks = smem;
    char* Vs = smem + 25600;
    const int qt = blockIdx.x, h = blockIdx.y, b = blockIdx.z;
    const int q0 = qt * 64;
    const int tid = threadIdx.x, w = tid >> 6, l = tid & 63;
    const int l15 = l & 15, g = l >> 4;
    char* Pw = smem + 25600 + 18432 + w * 2304;

    bf16x8 qf[6];
    const u16* qrow = q + (size_t)(b * L_ + q0 + w * 16 + l15) * QKS_ + h * QKD_;
#pragma unroll
    for (int kc = 0; kc < 6; ++kc) qf[kc] = ld8(qrow + kc * 32 + g * 8);

    const f32x4 zero = {0.f, 0.f, 0.f, 0.f};
    f32x4 o[8];
#pragma unroll
    for (int n = 0; n < 8; ++n) o[n] = zero;
    float m_r[4] = {-1e30f, -1e30f, -1e30f, -1e30f};
    float l_r[4] = {0.f, 0.f, 0.f, 0.f};

    const float scale = 0.07216878364870322f;  // 1/sqrt(192)
    const u16* kbase = k + (size_t)(b * L_) * QKS_ + h * QKD_;
    const u16* vtbase = vt + (size_t)(b * NHHD_ + h * HD_) * L_;

    for (int t = 0; t <= qt; ++t) {
        const int kv0 = t * 64;
        __syncthreads();
        // stage K tile: 64 rows x 24 chunks
#pragma unroll
        for (int i = 0; i < 6; ++i) {
            int idx = i * 256 + tid;
            int row = idx / 24, c = idx % 24;
            u32x4 d = *(const u32x4*)(kbase + (size_t)(kv0 + row) * QKS_ + c * 8);
            *(u32x4*)(Ks + row * 400 + c * 16) = d;
        }
        // stage Vt tile: 128 rows x 8 chunks
#pragma unroll
        for (int i = 0; i < 4; ++i) {
            int idx = i * 256 + tid;
            int dd = idx >> 3, c = idx & 7;
            u32x4 d = *(const u32x4*)(vtbase + (size_t)dd * L_ + kv0 + c * 8);
            *(u32x4*)(Vs + dd * 144 + c * 16) = d;
        }
        __syncthreads();

        f32x4 s[4];
#pragma unroll
        for (int n = 0; n < 4; ++n) {
            f32x4 acc = zero;
#pragma unroll
            for (int kc = 0; kc < 6; ++kc) {
                bf16x8 kb = ld8((const u16*)(Ks + (n * 16 + l15) * 400 + kc * 64 + g * 16));
                acc = mfma16(qf[kc], kb, acc);
            }
            s[n] = acc;
        }
        const bool diag = (t == qt);
#pragma unroll
        for (int r = 0; r < 4; ++r) {
            const int qabs = q0 + w * 16 + g * 4 + r;
            float mx = -1e30f;
#pragma unroll
            for (int n = 0; n < 4; ++n) {
                float v = s[n][r] * scale;
                if (diag && (kv0 + n * 16 + l15 > qabs)) v = -1e30f;
                s[n][r] = v;
                mx = fmaxf(mx, v);
            }
#pragma unroll
            for (int d = 1; d < 16; d <<= 1) mx = fmaxf(mx, __shfl_xor(mx, d));
            float mn = fmaxf(m_r[r], mx);
            float f = __expf(m_r[r] - mn);
            float rs = 0.f;
#pragma unroll
            for (int n = 0; n < 4; ++n) {
                float p = __expf(s[n][r] - mn);
                s[n][r] = p;
                rs += p;
            }
#pragma unroll
            for (int d = 1; d < 16; d <<= 1) rs += __shfl_xor(rs, d);
            l_r[r] = l_r[r] * f + rs;
            m_r[r] = mn;
#pragma unroll
            for (int n = 0; n < 8; ++n) o[n][r] *= f;
        }
        // P -> LDS (transpose through LDS for PV A-operand)
#pragma unroll
        for (int n = 0; n < 4; ++n)
#pragma unroll
            for (int r = 0; r < 4; ++r)
                *(u16*)(Pw + (g * 4 + r) * 144 + (n * 16 + l15) * 2) = f2bf(s[n][r]);
        __syncthreads();
#pragma unroll
        for (int ks = 0; ks < 2; ++ks) {
            bf16x8 pa = ld8((const u16*)(Pw + l15 * 144 + ks * 64 + g * 16));
#pragma unroll
            for (int n = 0; n < 8; ++n) {
                bf16x8 vb = ld8((const u16*)(Vs + (n * 16 + l15) * 144 + ks * 64 + g * 16));
                o[n] = mfma16(pa, vb, o[n]);
            }
        }
    }
#pragma unroll
    for (int r = 0; r < 4; ++r) {
        float inv = 1.f / l_r[r];
        const size_t rbase = (size_t)(b * L_ + q0 + w * 16 + g * 4 + r) * NHHD_ + h * HD_;
#pragma unroll
        for (int n = 0; n < 8; ++n) attn_o[rbase + n * 16 + l15] = f2bf(o[n][r] * inv);
    }
}

extern "C" void kernel_launch(void* const* d_in, const int* in_sizes, int n_in,
                              void* d_out, int out_size, void* d_ws, size_t ws_size,
                              hipStream_t stream) {
    (void)in_sizes; (void)n_in; (void)out_size; (void)ws_size;
    const float* x = (const float*)d_in[0];
    const float* wq_down = (const float*)d_in[1];
    const float* wq_up = (const float*)d_in[2];
    const float* wq_rope = (const float*)d_in[3];
    const float* wkv_down = (const float*)d_in[4];
    const float* wk_up = (const float*)d_in[5];
    const float* wv_up = (const float*)d_in[6];
    const float* wk_rope = (const float*)d_in[7];
    const float* wo = (const float*)d_in[8];

    u16* W = (u16*)d_ws;
    size_t off = 0;
    auto alloc = [&](size_t e) { u16* p = W + off; off += (e + 127) & ~(size_t)127; return p; };

    u16* xb     = alloc((size_t)BL_ * H_);        // x bf16
    u16* wqd_t  = alloc((size_t)QR_ * H_);        // 768 x 2048
    u16* wqu_t  = alloc((size_t)NHHD_ * QR_);     // 2048 x 768
    u16* wqr_t  = alloc((size_t)NH_ * RD_ * QR_); // 1024 x 768
    u16* wkvd_t = alloc((size_t)KVR_ * H_);       // 512 x 2048
    u16* wku_t  = alloc((size_t)NHHD_ * KVR_);    // 2048 x 512
    u16* wvu_t  = alloc((size_t)NHHD_ * KVR_);    // 2048 x 512
    u16* wkr_t  = alloc((size_t)128 * H_);        // 128(pad) x 2048
    u16* wo_t   = alloc((size_t)H_ * NHHD_);      // 2048 x 2048
    u16* q_lat  = alloc((size_t)BL_ * QR_);
    u16* kv_lat = alloc((size_t)BL_ * KVR_);
    u16* q_cont = alloc((size_t)BL_ * NHHD_);
    u16* q_rraw = alloc((size_t)BL_ * NH_ * RD_);
    u16* k_cont = alloc((size_t)BL_ * NHHD_);
    u16* v_buf  = alloc((size_t)BL_ * NHHD_);
    u16* k_rraw = alloc((size_t)BL_ * 128);
    u16* qbuf   = alloc((size_t)BL_ * QKS_);
    u16* kbuf   = alloc((size_t)BL_ * QKS_);
    u16* vt_buf = alloc((size_t)BL_ * NHHD_);
    u16* attn_o = alloc((size_t)BL_ * NHHD_);
    // total ~195 MB

    // 1. casts
    cast_bf16_kernel<<<(BL_ * H_ / 4 + 255) / 256, 256, 0, stream>>>(x, xb, BL_ * H_ / 4);
    cast_transpose<<<dim3(QR_ / 32, H_ / 32), 256, 0, stream>>>(wq_down, wqd_t, H_, QR_, QR_);
    cast_transpose<<<dim3(NHHD_ / 32, QR_ / 32), 256, 0, stream>>>(wq_up, wqu_t, QR_, NHHD_, NHHD_);
    cast_transpose<<<dim3(NH_ * RD_ / 32, QR_ / 32), 256, 0, stream>>>(wq_rope, wqr_t, QR_, NH_ * RD_, NH_ * RD_);
    cast_transpose<<<dim3(KVR_ / 32, H_ / 32), 256, 0, stream>>>(wkv_down, wkvd_t, H_, KVR_, KVR_);
    cast_transpose<<<dim3(NHHD_ / 32, KVR_ / 32), 256, 0, stream>>>(wk_up, wku_t, KVR_, NHHD_, NHHD_);
    cast_transpose<<<dim3(NHHD_ / 32, KVR_ / 32), 256, 0, stream>>>(wv_up, wvu_t, KVR_, NHHD_, NHHD_);
    cast_transpose<<<dim3(128 / 32, H_ / 32), 256, 0, stream>>>(wk_rope, wkr_t, H_, RD_, 128);
    cast_transpose<<<dim3(NHHD_ / 32, H_ / 32), 256, 0, stream>>>(wo, wo_t, NHHD_, H_, H_);

    // 2. projection GEMMs
    gemm_bt<0><<<dim3(QR_ / 128, BL_ / 128), 256, 0, stream>>>(xb, wqd_t, q_lat, BL_, QR_, H_);
    gemm_bt<0><<<dim3(KVR_ / 128, BL_ / 128), 256, 0, stream>>>(xb, wkvd_t, kv_lat, BL_, KVR_, H_);
    gemm_bt<0><<<dim3(1, BL_ / 128), 256, 0, stream>>>(xb, wkr_t, k_rraw, BL_, 128, H_);
    gemm_bt<0><<<dim3(NHHD_ / 128, BL_ / 128), 256, 0, stream>>>(q_lat, wqu_t, q_cont, BL_, NHHD_, QR_);
    gemm_bt<0><<<dim3(NH_ * RD_ / 128, BL_ / 128), 256, 0, stream>>>(q_lat, wqr_t, q_rraw, BL_, NH_ * RD_, QR_);
    gemm_bt<0><<<dim3(NHHD_ / 128, BL_ / 128), 256, 0, stream>>>(kv_lat, wku_t, k_cont, BL_, NHHD_, KVR_);
    gemm_bt<0><<<dim3(NHHD_ / 128, BL_ / 128), 256, 0, stream>>>(kv_lat, wvu_t, v_buf, BL_, NHHD_, KVR_);

    // 3. assemble q, k, vt
    pack_content<<<BL_ * NHHD_ / 8 / 256, 256, 0, stream>>>(q_cont, qbuf);
    pack_content<<<BL_ * NHHD_ / 8 / 256, 256, 0, stream>>>(k_cont, kbuf);
    rope_q_kernel<<<BL_ * NH_ * 32 / 256, 256, 0, stream>>>(q_rraw, qbuf);
    rope_k_kernel<<<BL_ * 32 / 256, 256, 0, stream>>>(k_rraw, kbuf);
    transpose_v<<<dim3(NHHD_ / 64, L_ / 64, B_), 256, 0, stream>>>(v_buf, vt_buf);

    // 4. attention
    flash_attn<<<dim3(L_ / 64, NH_, B_), 256, 0, stream>>>(qbuf, kbuf, vt_buf, attn_o);

    // 5. output projection (fp32 out)
    gemm_bt<1><<<dim3(H_ / 128, BL_ / 128), 256, 0, stream>>>(attn_o, wo_t, d_out, BL_, H_, NHHD_);
}

// Round 2
// 433.311 us; speedup vs baseline: 1.5047x; 1.5047x over previous
//
#include <hip/hip_runtime.h>

typedef unsigned short u16;
typedef unsigned int u32;
typedef unsigned long long u64;
typedef __bf16 bf16x8 __attribute__((ext_vector_type(8)));
typedef float f32x4 __attribute__((ext_vector_type(4)));
typedef float f32x16 __attribute__((ext_vector_type(16)));
typedef u32 u32x4 __attribute__((ext_vector_type(4)));

#define DEV static __device__ __forceinline__

constexpr int B_ = 2, L_ = 2048, H_ = 2048;
constexpr int NH_ = 16, HD_ = 128, RD_ = 64;
constexpr int QR_ = 768, KVR_ = 512;
constexpr int BL_ = B_ * L_;          // 4096 tokens
constexpr int QKD_ = HD_ + RD_;       // 192
constexpr int QKS_ = NH_ * QKD_;      // 3072
constexpr int NHHD_ = NH_ * HD_;      // 2048

DEV u16 f2bf(float f) {
    u32 u = __builtin_bit_cast(u32, f);
    u32 r = (u + 0x7fffu + ((u >> 16) & 1u)) >> 16;
    return (u16)r;
}
DEV float bf2f(u16 h) {
    u32 u = ((u32)h) << 16;
    return __builtin_bit_cast(float, u);
}
DEV u32 pk2(float lo, float hi) { return (u32)f2bf(lo) | ((u32)f2bf(hi) << 16); }
DEV bf16x8 ld8(const u16* p) { return __builtin_bit_cast(bf16x8, *(const u32x4*)p); }
DEV f32x4 mfma16(bf16x8 a, bf16x8 b, f32x4 c) {
    return __builtin_amdgcn_mfma_f32_16x16x32_bf16(a, b, c, 0, 0, 0);
}
DEV f32x16 mfma32(bf16x8 a, bf16x8 b, f32x16 c) {
    return __builtin_amdgcn_mfma_f32_32x32x16_bf16(a, b, c, 0, 0, 0);
}
DEV void gload16(const void* g, void* l) {
    __builtin_amdgcn_global_load_lds((const __attribute__((address_space(1))) void*)g,
                                     (__attribute__((address_space(3))) void*)l, 16, 0, 0);
}

// ---------------- elementwise cast: f32 -> bf16, 4 elems/thread ----------------
__global__ __launch_bounds__(256) void cast_bf16_kernel(const float* __restrict__ src,
                                                        u16* __restrict__ dst, int n4) {
    int i = blockIdx.x * 256 + threadIdx.x;
    if (i >= n4) return;
    float4 v = ((const float4*)src)[i];
    u64 pk = (u64)f2bf(v.x) | ((u64)f2bf(v.y) << 16) | ((u64)f2bf(v.z) << 32) | ((u64)f2bf(v.w) << 48);
    ((u64*)dst)[i] = pk;
}

// ------------- cast + transpose: src (K x N) f32 -> dst (dstN x K) bf16, zero-pad rows >= N -------------
__global__ __launch_bounds__(256) void cast_transpose(const float* __restrict__ src, u16* __restrict__ dst,
                                                      int K, int N, int dstN) {
    __shared__ float tile[32][33];
    int n0 = blockIdx.x * 32, k0 = blockIdx.y * 32;
    int tx = threadIdx.x & 31, ty = threadIdx.x >> 5;  // 32 x 8
#pragma unroll
    for (int i = 0; i < 4; ++i) {
        int kk = ty + i * 8;
        int n = n0 + tx;
        tile[kk][tx] = (n < N) ? src[(size_t)(k0 + kk) * N + n] : 0.f;
    }
    __syncthreads();
#pragma unroll
    for (int i = 0; i < 4; ++i) {
        int nn = ty + i * 8;
        dst[(size_t)(n0 + nn) * K + k0 + tx] = f2bf(tile[tx][nn]);
    }
}

// ---------------- GEMM (m97 structure): C = A(M x K, lda) * Bt(N x K)^T ----------------
// 128x128 tile, 4 waves (2x2), BK=32, global_load_lds width-16 staging, linear LDS [128][32].
template <int OUTF32>
__global__ __launch_bounds__(256, 2) void gemm_bt(const u16* __restrict__ A, int lda,
                                                  const u16* __restrict__ Bt,
                                                  void* __restrict__ Cv, int ldc, int K) {
    __shared__ u16 As[128 * 32];
    __shared__ u16 Bs[128 * 32];
    const int tid = threadIdx.x;
    const int l = tid & 63, w = tid >> 6;
    const int l15 = l & 15, g = l >> 4;
    const int wr = w >> 1, wc = w & 1;
    const int bm = blockIdx.y * 128, bn = blockIdx.x * 128;

    const f32x4 zero = {0.f, 0.f, 0.f, 0.f};
    f32x4 acc[4][4];
#pragma unroll
    for (int m = 0; m < 4; ++m)
#pragma unroll
        for (int n = 0; n < 4; ++n) acc[m][n] = zero;

    // staging coords: per call j, chunk idx = w*128 + j*64 + l ; row = idx>>2, kc = idx&3
    const int ar0 = w * 32 + (l >> 2), kc8 = (l & 3) * 8;
    const u16* aptr = A + (size_t)(bm + ar0) * lda + kc8;
    const u16* aptr2 = A + (size_t)(bm + ar0 + 16) * lda + kc8;
    const u16* bptr = Bt + (size_t)(bn + ar0) * K + kc8;
    const u16* bptr2 = Bt + (size_t)(bn + ar0 + 16) * K + kc8;
    u16* asl = As + w * 1024;
    u16* bsl = Bs + w * 1024;

    const int nK = K / 32;
    for (int kt = 0; kt < nK; ++kt) {
        const int ko = kt * 32;
        __syncthreads();
        gload16(aptr + ko, asl);
        gload16(aptr2 + ko, asl + 512);
        gload16(bptr + ko, bsl);
        gload16(bptr2 + ko, bsl + 512);
        __syncthreads();
        bf16x8 af[4], bfr[4];
#pragma unroll
        for (int m = 0; m < 4; ++m)
            af[m] = ld8(As + (wr * 64 + m * 16 + l15) * 32 + g * 8);
#pragma unroll
        for (int n = 0; n < 4; ++n)
            bfr[n] = ld8(Bs + (wc * 64 + n * 16 + l15) * 32 + g * 8);
#pragma unroll
        for (int m = 0; m < 4; ++m)
#pragma unroll
            for (int n = 0; n < 4; ++n) acc[m][n] = mfma16(af[m], bfr[n], acc[m][n]);
    }
#pragma unroll
    for (int m = 0; m < 4; ++m)
#pragma unroll
        for (int n = 0; n < 4; ++n)
#pragma unroll
            for (int r = 0; r < 4; ++r) {
                int row = bm + wr * 64 + m * 16 + g * 4 + r;
                int col = bn + wc * 64 + n * 16 + l15;
                if (OUTF32)
                    ((float*)Cv)[(size_t)row * ldc + col] = acc[m][n][r];
                else
                    ((u16*)Cv)[(size_t)row * ldc + col] = f2bf(acc[m][n][r]);
            }
}

// ------------- pack: src [BL][2048] (row stride S) -> dst [BL][3072] at h*192 + d (d<128) -------------
__global__ __launch_bounds__(256) void pack_content(const u16* __restrict__ src, int S,
                                                    u16* __restrict__ dst) {
    size_t i = (size_t)blockIdx.x * 256 + threadIdx.x;  // BL*2048/8
    int token = (int)(i >> 8), c = (int)(i & 255);
    int h = c >> 4, d8 = c & 15;
    u32x4 v = *(const u32x4*)(src + (size_t)token * S + c * 8);
    *(u32x4*)(dst + (size_t)token * QKS_ + h * QKD_ + d8 * 8) = v;
}

// ------------- RoPE on q_rope (cols h*64+i at stride S), write into q at h*192+128+i -------------
__global__ __launch_bounds__(256) void rope_q_kernel(const u16* __restrict__ src, int S,
                                                     u16* __restrict__ dst) {
    int idx = blockIdx.x * 256 + threadIdx.x;  // BL*NH*32
    int token = idx >> 9;
    int r = idx & 511;
    int h = r >> 5, i = r & 31;
    int pos = token & (L_ - 1);
    float ang = (float)pos * powf(10000.f, -(float)i * (1.f / 32.f));
    float c = cosf(ang), s = sinf(ang);
    float x1 = bf2f(src[(size_t)token * S + h * 64 + i]);
    float x2 = bf2f(src[(size_t)token * S + h * 64 + i + 32]);
    u16* base = dst + (size_t)token * QKS_ + h * QKD_ + HD_;
    base[i] = f2bf(x1 * c - x2 * s);
    base[i + 32] = f2bf(x2 * c + x1 * s);
}

// ------------- RoPE on k_rope (64 cols at stride S) + broadcast to all heads of k -------------
__global__ __launch_bounds__(256) void rope_k_kernel(const u16* __restrict__ src, int S,
                                                     u16* __restrict__ dst) {
    int idx = blockIdx.x * 256 + threadIdx.x;  // BL*32
    int token = idx >> 5, i = idx & 31;
    int pos = token & (L_ - 1);
    float ang = (float)pos * powf(10000.f, -(float)i * (1.f / 32.f));
    float c = cosf(ang), s = sinf(ang);
    float x1 = bf2f(src[(size_t)token * S + i]);
    float x2 = bf2f(src[(size_t)token * S + i + 32]);
    u16 o1 = f2bf(x1 * c - x2 * s);
    u16 o2 = f2bf(x2 * c + x1 * s);
    u16* base = dst + (size_t)token * QKS_ + HD_;
#pragma unroll
    for (int h = 0; h < NH_; ++h) {
        base[h * QKD_ + i] = o1;
        base[h * QKD_ + i + 32] = o2;
    }
}

// ------------- transpose v [BL][*] (stride S) -> vt [(b*2048+col)][L] -------------
__global__ __launch_bounds__(256) void transpose_v(const u16* __restrict__ v, int S,
                                                   u16* __restrict__ vt) {
    __shared__ u16 tile[64][72];
    int cb = blockIdx.x * 64, lb = blockIdx.y * 64, b = blockIdx.z;
    int tid = threadIdx.x;
    int tr = tid >> 3, tc = (tid & 7) * 8;
#pragma unroll
    for (int i = 0; i < 2; ++i) {
        int row = tr + i * 32;
        u32x4 d = *(const u32x4*)(v + (size_t)(b * L_ + lb + row) * S + cb + tc);
        *(u32x4*)&tile[row][tc] = d;
    }
    __syncthreads();
#pragma unroll
    for (int i = 0; i < 2; ++i) {
        int col = tr + i * 32;
        u16 tmp[8];
#pragma unroll
        for (int j = 0; j < 8; ++j) tmp[j] = tile[tc + j][col];
        *(u32x4*)(vt + (size_t)(b * NHHD_ + cb + col) * L_ + lb + tc) = *(u32x4*)tmp;
    }
}

// ------------- causal flash attention, swapped-QK 32x32 structure -------------
// grid (16, NH, B) reversed-x; 4 waves, wave w owns q rows [q0+32w, q0+32w+32).
// QK^T: mfma32(A=K, B=Q) -> S^T (lane owns q-col = lane&31, 32 k-slots across 2 halves).
// Softmax lane-local (+1 shfl_xor(32)). PV transposed: O^T = mfma32(A=V^T, B=P^T).
// K LDS [64][192] + V^T LDS [128][64], both XOR-swizzled (granule ^= row&7).
__global__ __launch_bounds__(256, 2) void flash_attn(const u16* __restrict__ q, const u16* __restrict__ k,
                                                     const u16* __restrict__ vt, u16* __restrict__ attn_o) {
    __shared__ __align__(16) u16 Ks[64 * 192];   // 24576 B
    __shared__ __align__(16) u16 Vs[128 * 64];   // 16384 B
    const int qtile = (int)(gridDim.x - 1 - blockIdx.x);  // big tiles first
    const int h = blockIdx.y, b = blockIdx.z;
    const int q0 = qtile * 128;
    const int tid = threadIdx.x, w = tid >> 6, l = tid & 63;
    const int ql = l & 31, hi = l >> 5;
    const int qabs = q0 + w * 32 + ql;
    const int sw = (ql & 7);  // read-side swizzle key (row&7 == ql&7 for all our rows)

    // Q fragments: 12 chunks of 16 dims
    bf16x8 qf[12];
    {
        const u16* qrow = q + (size_t)(b * L_ + qabs) * QKS_ + h * QKD_;
#pragma unroll
        for (int c = 0; c < 12; ++c) qf[c] = ld8(qrow + c * 16 + hi * 8);
    }

    f32x16 o[4];
#pragma unroll
    for (int n = 0; n < 4; ++n)
#pragma unroll
        for (int r = 0; r < 16; ++r) o[n][r] = 0.f;
    float m2 = -1e30f, lsum = 0.f;

    constexpr float scale2 = 0.07216878364870322f * 1.4426950408889634f;  // 1/sqrt(192) * log2(e)
    const u16* kbase = k + (size_t)(b * L_) * QKS_ + h * QKD_;
    const u16* vtbase = vt + (size_t)(b * NHHD_ + h * HD_) * L_;

    const int nt = 2 * qtile + 2;
    for (int t = 0; t < nt; ++t) {
        const int kv0 = t * 64;
        __syncthreads();
        // stage K tile [64][192], swizzled: granule ^= row&7
#pragma unroll
        for (int j = 0; j < 6; ++j) {
            int idx = j * 256 + tid;
            int row = idx / 24, gr = idx - row * 24;
            u32x4 d = *(const u32x4*)(kbase + (size_t)(kv0 + row) * QKS_ + gr * 8);
            *(u32x4*)((char*)Ks + row * 384 + ((gr ^ (row & 7)) * 16)) = d;
        }
        // stage V^T tile [128][64], swizzled
#pragma unroll
        for (int j = 0; j < 4; ++j) {
            int idx = j * 256 + tid;
            int row = idx >> 3, gr = idx & 7;
            u32x4 d = *(const u32x4*)(vtbase + (size_t)row * L_ + kv0 + gr * 8);
            *(u32x4*)((char*)Vs + row * 128 + ((gr ^ (row & 7)) * 16)) = d;
        }
        __syncthreads();

        // QK^T: S^T[kv][q], two 32-row halves
        f32x16 s0, s1;
#pragma unroll
        for (int r = 0; r < 16; ++r) { s0[r] = 0.f; s1[r] = 0.f; }
#pragma unroll
        for (int c = 0; c < 12; ++c) {
            int gsw = ((2 * c + hi) ^ sw) * 16;
            bf16x8 k0 = ld8((const u16*)((char*)Ks + ql * 384 + gsw));
            bf16x8 k1 = ld8((const u16*)((char*)Ks + (32 + ql) * 384 + gsw));
            s0 = mfma32(k0, qf[c], s0);
            s1 = mfma32(k1, qf[c], s1);
        }

        // softmax (exp2 domain), lane-local + one cross-half exchange
        const bool domask = (kv0 + 63 > q0);
        float mx = -3e38f;
#pragma unroll
        for (int r = 0; r < 16; ++r) {
            const int kk = (r & 3) + 8 * (r >> 2) + 4 * hi;
            float x0 = s0[r] * scale2;
            float x1 = s1[r] * scale2;
            if (domask) {
                if (kv0 + kk > qabs) x0 = -3e38f;
                if (kv0 + 32 + kk > qabs) x1 = -3e38f;
            }
            s0[r] = x0; s1[r] = x1;
            mx = fmaxf(mx, fmaxf(x0, x1));
        }
        mx = fmaxf(mx, __shfl_xor(mx, 32));
        const float mnew = fmaxf(m2, mx);
        const float f = exp2f(m2 - mnew);
        m2 = mnew;
        float sl = 0.f;
#pragma unroll
        for (int r = 0; r < 16; ++r) {
            float p0 = exp2f(s0[r] - m2);
            float p1 = exp2f(s1[r] - m2);
            s0[r] = p0; s1[r] = p1;
            sl += p0 + p1;
        }
        lsum = lsum * f + sl;
#pragma unroll
        for (int n = 0; n < 4; ++n)
#pragma unroll
            for (int r = 0; r < 16; ++r) o[n][r] *= f;

        // P -> B-fragments (k-runs of 8) via pack + cross-half exchange, then PV (transposed)
#pragma unroll
        for (int c = 0; c < 4; ++c) {
            const int rb = 8 * (c & 1);
            float p0, p1, p2, p3, p4, p5, p6, p7;
            if (c < 2) {
                p0 = s0[rb + 0]; p1 = s0[rb + 1]; p2 = s0[rb + 2]; p3 = s0[rb + 3];
                p4 = s0[rb + 4]; p5 = s0[rb + 5]; p6 = s0[rb + 6]; p7 = s0[rb + 7];
            } else {
                p0 = s1[rb + 0]; p1 = s1[rb + 1]; p2 = s1[rb + 2]; p3 = s1[rb + 3];
                p4 = s1[rb + 4]; p5 = s1[rb + 5]; p6 = s1[rb + 6]; p7 = s1[rb + 7];
            }
            u32 a0 = pk2(p0, p1), a1 = pk2(p2, p3);
            u32 b0 = pk2(p4, p5), b1 = pk2(p6, p7);
            u32 pa0 = (u32)__shfl_xor((int)a0, 32);
            u32 pa1 = (u32)__shfl_xor((int)a1, 32);
            u32 pb0 = (u32)__shfl_xor((int)b0, 32);
            u32 pb1 = (u32)__shfl_xor((int)b1, 32);
            u32x4 pw = {hi ? pb0 : a0, hi ? pb1 : a1, hi ? b0 : pa0, hi ? b1 : pa1};
            bf16x8 pf = __builtin_bit_cast(bf16x8, pw);
            const int gsw = ((2 * c + hi) ^ sw) * 16;
#pragma unroll
            for (int n = 0; n < 4; ++n) {
                bf16x8 vf = ld8((const u16*)((char*)Vs + (32 * n + ql) * 128 + gsw));
                o[n] = mfma32(vf, pf, o[n]);
            }
        }
    }

    // finalize: combine halves' partial sums, normalize, write O^T back as [token][h*128+d]
    const float ltot = lsum + __shfl_xor(lsum, 32);
    const float inv = 1.f / ltot;
    u16* obase = attn_o + (size_t)(b * L_ + qabs) * NHHD_ + h * HD_;
#pragma unroll
    for (int n = 0; n < 4; ++n)
#pragma unroll
        for (int rg = 0; rg < 4; ++rg) {
            const int d0 = 32 * n + 8 * rg + 4 * hi;
            u64 pk = (u64)f2bf(o[n][4 * rg + 0] * inv) |
                     ((u64)f2bf(o[n][4 * rg + 1] * inv) << 16) |
                     ((u64)f2bf(o[n][4 * rg + 2] * inv) << 32) |
                     ((u64)f2bf(o[n][4 * rg + 3] * inv) << 48);
            *(u64*)(obase + d0) = pk;
        }
}

extern "C" void kernel_launch(void* const* d_in, const int* in_sizes, int n_in,
                              void* d_out, int out_size, void* d_ws, size_t ws_size,
                              hipStream_t stream) {
    (void)in_sizes; (void)n_in; (void)out_size; (void)ws_size;
    const float* x = (const float*)d_in[0];
    const float* wq_down = (const float*)d_in[1];
    const float* wq_up = (const float*)d_in[2];
    const float* wq_rope = (const float*)d_in[3];
    const float* wkv_down = (const float*)d_in[4];
    const float* wk_up = (const float*)d_in[5];
    const float* wv_up = (const float*)d_in[6];
    const float* wk_rope = (const float*)d_in[7];
    const float* wo = (const float*)d_in[8];

    u16* W = (u16*)d_ws;
    size_t off = 0;
    auto alloc = [&](size_t e) { u16* p = W + off; off += (e + 127) & ~(size_t)127; return p; };

    u16* xb    = alloc((size_t)BL_ * H_);        // 4096 x 2048
    u16* Wdn   = alloc((size_t)1408 * H_);       // [768 qd | 512 kvd | 128 kr(pad)] x 2048
    u16* Wupq  = alloc((size_t)3072 * QR_);      // [2048 qu | 1024 qr] x 768
    u16* Wupkv = alloc((size_t)4096 * KVR_);     // [2048 ku | 2048 vu] x 512
    u16* Wo_t  = alloc((size_t)H_ * NHHD_);      // 2048 x 2048
    u16* C1    = alloc((size_t)BL_ * 1408);      // latents: q_lat | kv_lat | k_rope_raw
    u16* C2    = alloc((size_t)BL_ * 3072);      // q_content | q_rope_raw
    u16* C3    = alloc((size_t)BL_ * 4096);      // k_content | v
    u16* qbuf  = alloc((size_t)BL_ * QKS_);
    u16* kbuf  = alloc((size_t)BL_ * QKS_);
    u16* vt    = alloc((size_t)BL_ * NHHD_);
    u16* attn_o = alloc((size_t)BL_ * NHHD_);
    // total ~194 MB

    // 1. casts + fused weight transposes
    cast_bf16_kernel<<<(BL_ * H_ / 4 + 255) / 256, 256, 0, stream>>>(x, xb, BL_ * H_ / 4);
    cast_transpose<<<dim3(QR_ / 32, H_ / 32), 256, 0, stream>>>(wq_down, Wdn, H_, QR_, QR_);
    cast_transpose<<<dim3(KVR_ / 32, H_ / 32), 256, 0, stream>>>(wkv_down, Wdn + (size_t)768 * H_, H_, KVR_, KVR_);
    cast_transpose<<<dim3(128 / 32, H_ / 32), 256, 0, stream>>>(wk_rope, Wdn + (size_t)1280 * H_, H_, RD_, 128);
    cast_transpose<<<dim3(NHHD_ / 32, QR_ / 32), 256, 0, stream>>>(wq_up, Wupq, QR_, NHHD_, NHHD_);
    cast_transpose<<<dim3(1024 / 32, QR_ / 32), 256, 0, stream>>>(wq_rope, Wupq + (size_t)2048 * QR_, QR_, 1024, 1024);
    cast_transpose<<<dim3(NHHD_ / 32, KVR_ / 32), 256, 0, stream>>>(wk_up, Wupkv, KVR_, NHHD_, NHHD_);
    cast_transpose<<<dim3(NHHD_ / 32, KVR_ / 32), 256, 0, stream>>>(wv_up, Wupkv + (size_t)2048 * KVR_, KVR_, NHHD_, NHHD_);
    cast_transpose<<<dim3(NHHD_ / 32, H_ / 32), 256, 0, stream>>>(wo, Wo_t, NHHD_, H_, H_);

    // 2. fused projection GEMMs
    gemm_bt<0><<<dim3(1408 / 128, BL_ / 128), 256, 0, stream>>>(xb, H_, Wdn, C1, 1408, H_);
    gemm_bt<0><<<dim3(3072 / 128, BL_ / 128), 256, 0, stream>>>(C1, 1408, Wupq, C2, 3072, QR_);
    gemm_bt<0><<<dim3(4096 / 128, BL_ / 128), 256, 0, stream>>>(C1 + 768, 1408, Wupkv, C3, 4096, KVR_);

    // 3. assemble q, k, vt
    pack_content<<<BL_ * NHHD_ / 8 / 256, 256, 0, stream>>>(C2, 3072, qbuf);
    pack_content<<<BL_ * NHHD_ / 8 / 256, 256, 0, stream>>>(C3, 4096, kbuf);
    rope_q_kernel<<<BL_ * NH_ * 32 / 256, 256, 0, stream>>>(C2 + 2048, 3072, qbuf);
    rope_k_kernel<<<BL_ * 32 / 256, 256, 0, stream>>>(C1 + 1280, 1408, kbuf);
    transpose_v<<<dim3(NHHD_ / 64, L_ / 64, B_), 256, 0, stream>>>(C3 + 2048, 4096, vt);

    // 4. attention
    flash_attn<<<dim3(L_ / 128, NH_, B_), 256, 0, stream>>>(qbuf, kbuf, vt, attn_o);

    // 5. output projection (fp32 out)
    gemm_bt<1><<<dim3(H_ / 128, BL_ / 128), 256, 0, stream>>>(attn_o, NHHD_, Wo_t, d_out, H_, NHHD_);
}

// Round 3
// 351.565 us; speedup vs baseline: 1.8545x; 1.2325x over previous
//
#include <hip/hip_runtime.h>

typedef unsigned short u16;
typedef unsigned int u32;
typedef unsigned long long u64;
typedef __bf16 bf16x8 __attribute__((ext_vector_type(8)));
typedef float f32x4 __attribute__((ext_vector_type(4)));
typedef float f32x16 __attribute__((ext_vector_type(16)));
typedef u32 u32x4 __attribute__((ext_vector_type(4)));

#define DEV static __device__ __forceinline__

constexpr int B_ = 2, L_ = 2048, H_ = 2048;
constexpr int NH_ = 16, HD_ = 128, RD_ = 64;
constexpr int QR_ = 768, KVR_ = 512;
constexpr int BL_ = B_ * L_;          // 4096 tokens
constexpr int QKD_ = HD_ + RD_;       // 192
constexpr int QKS_ = NH_ * QKD_;      // 3072
constexpr int NHHD_ = NH_ * HD_;      // 2048

DEV u16 f2bf(float f) {
    u32 u = __builtin_bit_cast(u32, f);
    u32 r = (u + 0x7fffu + ((u >> 16) & 1u)) >> 16;
    return (u16)r;
}
DEV float bf2f(u16 h) {
    u32 u = ((u32)h) << 16;
    return __builtin_bit_cast(float, u);
}
DEV u32 pk2(float lo, float hi) { return (u32)f2bf(lo) | ((u32)f2bf(hi) << 16); }
DEV bf16x8 ld8(const u16* p) { return __builtin_bit_cast(bf16x8, *(const u32x4*)p); }
DEV f32x4 mfma16(bf16x8 a, bf16x8 b, f32x4 c) {
    return __builtin_amdgcn_mfma_f32_16x16x32_bf16(a, b, c, 0, 0, 0);
}
DEV f32x16 mfma32(bf16x8 a, bf16x8 b, f32x16 c) {
    return __builtin_amdgcn_mfma_f32_32x32x16_bf16(a, b, c, 0, 0, 0);
}
DEV void gload16(const void* g, void* l) {
    __builtin_amdgcn_global_load_lds((const __attribute__((address_space(1))) void*)g,
                                     (__attribute__((address_space(3))) void*)l, 16, 0, 0);
}

// ---------------- elementwise cast: f32 -> bf16, 4 elems/thread ----------------
__global__ __launch_bounds__(256) void cast_bf16_kernel(const float* __restrict__ src,
                                                        u16* __restrict__ dst, int n4) {
    int i = blockIdx.x * 256 + threadIdx.x;
    if (i >= n4) return;
    float4 v = ((const float4*)src)[i];
    u64 pk = (u64)f2bf(v.x) | ((u64)f2bf(v.y) << 16) | ((u64)f2bf(v.z) << 32) | ((u64)f2bf(v.w) << 48);
    ((u64*)dst)[i] = pk;
}

// ------------- cast + transpose: src (K x N) f32 -> dst (dstN x K) bf16, zero-pad rows >= N -------------
__global__ __launch_bounds__(256) void cast_transpose(const float* __restrict__ src, u16* __restrict__ dst,
                                                      int K, int N, int dstN) {
    __shared__ float tile[32][33];
    int n0 = blockIdx.x * 32, k0 = blockIdx.y * 32;
    int tx = threadIdx.x & 31, ty = threadIdx.x >> 5;  // 32 x 8
#pragma unroll
    for (int i = 0; i < 4; ++i) {
        int kk = ty + i * 8;
        int n = n0 + tx;
        tile[kk][tx] = (n < N) ? src[(size_t)(k0 + kk) * N + n] : 0.f;
    }
    __syncthreads();
#pragma unroll
    for (int i = 0; i < 4; ++i) {
        int nn = ty + i * 8;
        dst[(size_t)(n0 + nn) * K + k0 + tx] = f2bf(tile[tx][nn]);
    }
}

// ---------------- GEMM (m97 structure): C = A(M x K, lda) * Bt(N x K)^T ----------------
template <int OUTF32>
__global__ __launch_bounds__(256, 2) void gemm_bt(const u16* __restrict__ A, int lda,
                                                  const u16* __restrict__ Bt,
                                                  void* __restrict__ Cv, int ldc, int K) {
    __shared__ u16 As[128 * 32];
    __shared__ u16 Bs[128 * 32];
    const int tid = threadIdx.x;
    const int l = tid & 63, w = tid >> 6;
    const int l15 = l & 15, g = l >> 4;
    const int wr = w >> 1, wc = w & 1;
    const int bm = blockIdx.y * 128, bn = blockIdx.x * 128;

    const f32x4 zero = {0.f, 0.f, 0.f, 0.f};
    f32x4 acc[4][4];
#pragma unroll
    for (int m = 0; m < 4; ++m)
#pragma unroll
        for (int n = 0; n < 4; ++n) acc[m][n] = zero;

    const int ar0 = w * 32 + (l >> 2), kc8 = (l & 3) * 8;
    const u16* aptr = A + (size_t)(bm + ar0) * lda + kc8;
    const u16* aptr2 = A + (size_t)(bm + ar0 + 16) * lda + kc8;
    const u16* bptr = Bt + (size_t)(bn + ar0) * K + kc8;
    const u16* bptr2 = Bt + (size_t)(bn + ar0 + 16) * K + kc8;
    u16* asl = As + w * 1024;
    u16* bsl = Bs + w * 1024;

    const int nK = K / 32;
    for (int kt = 0; kt < nK; ++kt) {
        const int ko = kt * 32;
        __syncthreads();
        gload16(aptr + ko, asl);
        gload16(aptr2 + ko, asl + 512);
        gload16(bptr + ko, bsl);
        gload16(bptr2 + ko, bsl + 512);
        __syncthreads();
        bf16x8 af[4], bfr[4];
#pragma unroll
        for (int m = 0; m < 4; ++m)
            af[m] = ld8(As + (wr * 64 + m * 16 + l15) * 32 + g * 8);
#pragma unroll
        for (int n = 0; n < 4; ++n)
            bfr[n] = ld8(Bs + (wc * 64 + n * 16 + l15) * 32 + g * 8);
#pragma unroll
        for (int m = 0; m < 4; ++m)
#pragma unroll
            for (int n = 0; n < 4; ++n) acc[m][n] = mfma16(af[m], bfr[n], acc[m][n]);
    }
#pragma unroll
    for (int m = 0; m < 4; ++m)
#pragma unroll
        for (int n = 0; n < 4; ++n)
#pragma unroll
            for (int r = 0; r < 4; ++r) {
                int row = bm + wr * 64 + m * 16 + g * 4 + r;
                int col = bn + wc * 64 + n * 16 + l15;
                if (OUTF32)
                    ((float*)Cv)[(size_t)row * ldc + col] = acc[m][n][r];
                else
                    ((u16*)Cv)[(size_t)row * ldc + col] = f2bf(acc[m][n][r]);
            }
}

// ------------- pack: src [BL][2048] (row stride S) -> dst [BL][3072] at h*192 + d (d<128) -------------
__global__ __launch_bounds__(256) void pack_content(const u16* __restrict__ src, int S,
                                                    u16* __restrict__ dst) {
    size_t i = (size_t)blockIdx.x * 256 + threadIdx.x;  // BL*2048/8
    int token = (int)(i >> 8), c = (int)(i & 255);
    int h = c >> 4, d8 = c & 15;
    u32x4 v = *(const u32x4*)(src + (size_t)token * S + c * 8);
    *(u32x4*)(dst + (size_t)token * QKS_ + h * QKD_ + d8 * 8) = v;
}

// ------------- RoPE on q_rope (cols h*64+i at stride S), write into q at h*192+128+i -------------
__global__ __launch_bounds__(256) void rope_q_kernel(const u16* __restrict__ src, int S,
                                                     u16* __restrict__ dst) {
    int idx = blockIdx.x * 256 + threadIdx.x;  // BL*NH*32
    int token = idx >> 9;
    int r = idx & 511;
    int h = r >> 5, i = r & 31;
    int pos = token & (L_ - 1);
    // 10000^(-i/32) = exp2(-i/32 * log2(10000))
    float ang = (float)pos * exp2f((float)i * (-13.287712379549449f / 32.f));
    float c = cosf(ang), s = sinf(ang);
    float x1 = bf2f(src[(size_t)token * S + h * 64 + i]);
    float x2 = bf2f(src[(size_t)token * S + h * 64 + i + 32]);
    u16* base = dst + (size_t)token * QKS_ + h * QKD_ + HD_;
    base[i] = f2bf(x1 * c - x2 * s);
    base[i + 32] = f2bf(x2 * c + x1 * s);
}

// ------------- RoPE on k_rope (64 cols at stride S) + broadcast to all heads of k -------------
__global__ __launch_bounds__(256) void rope_k_kernel(const u16* __restrict__ src, int S,
                                                     u16* __restrict__ dst) {
    int idx = blockIdx.x * 256 + threadIdx.x;  // BL*32
    int token = idx >> 5, i = idx & 31;
    int pos = token & (L_ - 1);
    float ang = (float)pos * exp2f((float)i * (-13.287712379549449f / 32.f));
    float c = cosf(ang), s = sinf(ang);
    float x1 = bf2f(src[(size_t)token * S + i]);
    float x2 = bf2f(src[(size_t)token * S + i + 32]);
    u16 o1 = f2bf(x1 * c - x2 * s);
    u16 o2 = f2bf(x2 * c + x1 * s);
    u16* base = dst + (size_t)token * QKS_ + HD_;
#pragma unroll
    for (int h = 0; h < NH_; ++h) {
        base[h * QKD_ + i] = o1;
        base[h * QKD_ + i + 32] = o2;
    }
}

// ------------- transpose v [BL][*] (stride S) -> vt [(b*2048+col)][L] -------------
__global__ __launch_bounds__(256) void transpose_v(const u16* __restrict__ v, int S,
                                                   u16* __restrict__ vt) {
    __shared__ u16 tile[64][72];
    int cb = blockIdx.x * 64, lb = blockIdx.y * 64, b = blockIdx.z;
    int tid = threadIdx.x;
    int tr = tid >> 3, tc = (tid & 7) * 8;
#pragma unroll
    for (int i = 0; i < 2; ++i) {
        int row = tr + i * 32;
        u32x4 d = *(const u32x4*)(v + (size_t)(b * L_ + lb + row) * S + cb + tc);
        *(u32x4*)&tile[row][tc] = d;
    }
    __syncthreads();
#pragma unroll
    for (int i = 0; i < 2; ++i) {
        int col = tr + i * 32;
        u16 tmp[8];
#pragma unroll
        for (int j = 0; j < 8; ++j) tmp[j] = tile[tc + j][col];
        *(u32x4*)(vt + (size_t)(b * NHHD_ + cb + col) * L_ + lb + tc) = *(u32x4*)tmp;
    }
}

// ------------- causal flash attention, swapped-QK 32x32, paired qtiles + dbuf prefetch -------------
// grid (8, NH, B); block p handles qtiles p and 15-p (34 KV-tiles total -> perfectly balanced).
// Staging via global_load_lds (linear LDS dest); XOR swizzle done by permuting the GLOBAL
// source granule (lane writing LDS slot (row,gr) fetches global granule gr^(row&7)) so the
// read-side swizzle is unchanged. K and V double-buffered; tile t+1 issued before compute t.
__global__ __launch_bounds__(256, 1) void flash_attn(const u16* __restrict__ q, const u16* __restrict__ k,
                                                     const u16* __restrict__ vt, u16* __restrict__ attn_o) {
    __shared__ __align__(16) u16 Ks[2][64 * 192];   // 2 x 24576 B
    __shared__ __align__(16) u16 Vs[2][128 * 64];   // 2 x 16384 B
    const int p = blockIdx.x, h = blockIdx.y, b = blockIdx.z;
    const int tid = threadIdx.x, w = tid >> 6, l = tid & 63;
    const int ql = l & 31, hi = l >> 5;
    const int sw = ql & 7;

    const u16* kbase = k + (size_t)(b * L_) * QKS_ + h * QKD_;
    const u16* vtbase = vt + (size_t)(b * NHHD_ + h * HD_) * L_;

    // per-lane pre-swizzled global source offsets (elements within a tile)
    int koff[6], voff[4];
#pragma unroll
    for (int j = 0; j < 6; ++j) {
        int off = j * 4096 + tid * 16;   // byte offset of this lane's LDS slot in the K tile
        int row = off / 384;
        int gr = (off % 384) / 16;
        koff[j] = row * QKS_ + (gr ^ (row & 7)) * 8;
    }
#pragma unroll
    for (int j = 0; j < 4; ++j) {
        int off = j * 4096 + tid * 16;
        int row = off >> 7;
        int gr = (off >> 4) & 7;
        voff[j] = row * L_ + (gr ^ (row & 7)) * 8;
    }

    auto STAGE = [&](int buf, int kv0) {
        const u16* kb = kbase + (size_t)kv0 * QKS_;
#pragma unroll
        for (int j = 0; j < 6; ++j)
            gload16(kb + koff[j], (u16*)Ks[buf] + j * 2048 + w * 512);
        const u16* vb = vtbase + kv0;
#pragma unroll
        for (int j = 0; j < 4; ++j)
            gload16(vb + voff[j], (u16*)Vs[buf] + j * 2048 + w * 512);
    };

    constexpr float scale2 = 0.07216878364870322f * 1.4426950408889634f;  // 1/sqrt(192) * log2(e)

    for (int half = 0; half < 2; ++half) {
        const int qtile = half ? 15 - p : p;
        const int q0 = qtile * 128;
        const int qabs = q0 + w * 32 + ql;

        bf16x8 qf[12];
        {
            const u16* qrow = q + (size_t)(b * L_ + qabs) * QKS_ + h * QKD_;
#pragma unroll
            for (int c = 0; c < 12; ++c) qf[c] = ld8(qrow + c * 16 + hi * 8);
        }
        f32x16 o[4];
#pragma unroll
        for (int n = 0; n < 4; ++n)
#pragma unroll
            for (int r = 0; r < 16; ++r) o[n][r] = 0.f;
        float m2 = -1e30f, lsum = 0.f;

        const int nt = 2 * qtile + 2;
        STAGE(0, 0);
        for (int t = 0; t < nt; ++t) {
            __syncthreads();   // drains vmcnt+lgkmcnt: tile t landed, buf (t+1)&1 free
            if (t + 1 < nt) STAGE((t + 1) & 1, (t + 1) * 64);
            const u16* Kb = Ks[t & 1];
            const u16* Vb = Vs[t & 1];
            const int kv0 = t * 64;

            // QK^T: S^T[kv][q], two 32-row halves
            f32x16 s0, s1;
#pragma unroll
            for (int r = 0; r < 16; ++r) { s0[r] = 0.f; s1[r] = 0.f; }
#pragma unroll
            for (int c = 0; c < 12; ++c) {
                int gsw = ((2 * c + hi) ^ sw) * 16;
                bf16x8 k0 = ld8((const u16*)((const char*)Kb + ql * 384 + gsw));
                bf16x8 k1 = ld8((const u16*)((const char*)Kb + (32 + ql) * 384 + gsw));
                s0 = mfma32(k0, qf[c], s0);
                s1 = mfma32(k1, qf[c], s1);
            }

            // softmax (exp2 domain), lane-local + one cross-half exchange
            const bool domask = (kv0 + 63 > q0);
            float mx = -3e38f;
#pragma unroll
            for (int r = 0; r < 16; ++r) {
                const int kk = (r & 3) + 8 * (r >> 2) + 4 * hi;
                float x0 = s0[r] * scale2;
                float x1 = s1[r] * scale2;
                if (domask) {
                    if (kv0 + kk > qabs) x0 = -3e38f;
                    if (kv0 + 32 + kk > qabs) x1 = -3e38f;
                }
                s0[r] = x0; s1[r] = x1;
                mx = fmaxf(mx, fmaxf(x0, x1));
            }
            mx = fmaxf(mx, __shfl_xor(mx, 32));
            const float mnew = fmaxf(m2, mx);
            const float f = exp2f(m2 - mnew);
            m2 = mnew;
            float sl = 0.f;
#pragma unroll
            for (int r = 0; r < 16; ++r) {
                float p0 = exp2f(s0[r] - m2);
                float p1 = exp2f(s1[r] - m2);
                s0[r] = p0; s1[r] = p1;
                sl += p0 + p1;
            }
            lsum = lsum * f + sl;
#pragma unroll
            for (int n = 0; n < 4; ++n)
#pragma unroll
                for (int r = 0; r < 16; ++r) o[n][r] *= f;

            // P -> B-fragments via pack + cross-half exchange, then PV (transposed)
#pragma unroll
            for (int c = 0; c < 4; ++c) {
                const int rb = 8 * (c & 1);
                float p0, p1, p2, p3, p4, p5, p6, p7;
                if (c < 2) {
                    p0 = s0[rb + 0]; p1 = s0[rb + 1]; p2 = s0[rb + 2]; p3 = s0[rb + 3];
                    p4 = s0[rb + 4]; p5 = s0[rb + 5]; p6 = s0[rb + 6]; p7 = s0[rb + 7];
                } else {
                    p0 = s1[rb + 0]; p1 = s1[rb + 1]; p2 = s1[rb + 2]; p3 = s1[rb + 3];
                    p4 = s1[rb + 4]; p5 = s1[rb + 5]; p6 = s1[rb + 6]; p7 = s1[rb + 7];
                }
                u32 a0 = pk2(p0, p1), a1 = pk2(p2, p3);
                u32 b0 = pk2(p4, p5), b1 = pk2(p6, p7);
                u32 pa0 = (u32)__shfl_xor((int)a0, 32);
                u32 pa1 = (u32)__shfl_xor((int)a1, 32);
                u32 pb0 = (u32)__shfl_xor((int)b0, 32);
                u32 pb1 = (u32)__shfl_xor((int)b1, 32);
                u32x4 pw = {hi ? pb0 : a0, hi ? pb1 : a1, hi ? b0 : pa0, hi ? b1 : pa1};
                bf16x8 pf = __builtin_bit_cast(bf16x8, pw);
                const int gsw = ((2 * c + hi) ^ sw) * 16;
#pragma unroll
                for (int n = 0; n < 4; ++n) {
                    bf16x8 vf = ld8((const u16*)((const char*)Vb + (32 * n + ql) * 128 + gsw));
                    o[n] = mfma32(vf, pf, o[n]);
                }
            }
        }

        // finalize: combine halves' sums, normalize, write O^T as [token][h*128+d]
        const float ltot = lsum + __shfl_xor(lsum, 32);
        const float inv = 1.f / ltot;
        u16* obase = attn_o + (size_t)(b * L_ + qabs) * NHHD_ + h * HD_;
#pragma unroll
        for (int n = 0; n < 4; ++n)
#pragma unroll
            for (int rg = 0; rg < 4; ++rg) {
                const int d0 = 32 * n + 8 * rg + 4 * hi;
                u64 pk = (u64)f2bf(o[n][4 * rg + 0] * inv) |
                         ((u64)f2bf(o[n][4 * rg + 1] * inv) << 16) |
                         ((u64)f2bf(o[n][4 * rg + 2] * inv) << 32) |
                         ((u64)f2bf(o[n][4 * rg + 3] * inv) << 48);
                *(u64*)(obase + d0) = pk;
            }
    }
}

extern "C" void kernel_launch(void* const* d_in, const int* in_sizes, int n_in,
                              void* d_out, int out_size, void* d_ws, size_t ws_size,
                              hipStream_t stream) {
    (void)in_sizes; (void)n_in; (void)out_size; (void)ws_size;
    const float* x = (const float*)d_in[0];
    const float* wq_down = (const float*)d_in[1];
    const float* wq_up = (const float*)d_in[2];
    const float* wq_rope = (const float*)d_in[3];
    const float* wkv_down = (const float*)d_in[4];
    const float* wk_up = (const float*)d_in[5];
    const float* wv_up = (const float*)d_in[6];
    const float* wk_rope = (const float*)d_in[7];
    const float* wo = (const float*)d_in[8];

    u16* W = (u16*)d_ws;
    size_t off = 0;
    auto alloc = [&](size_t e) { u16* p = W + off; off += (e + 127) & ~(size_t)127; return p; };

    u16* xb    = alloc((size_t)BL_ * H_);        // 4096 x 2048
    u16* Wdn   = alloc((size_t)1408 * H_);       // [768 qd | 512 kvd | 128 kr(pad)] x 2048
    u16* Wupq  = alloc((size_t)3072 * QR_);      // [2048 qu | 1024 qr] x 768
    u16* Wupkv = alloc((size_t)4096 * KVR_);     // [2048 ku | 2048 vu] x 512
    u16* Wo_t  = alloc((size_t)H_ * NHHD_);      // 2048 x 2048
    u16* C1    = alloc((size_t)BL_ * 1408);      // latents: q_lat | kv_lat | k_rope_raw
    u16* C2    = alloc((size_t)BL_ * 3072);      // q_content | q_rope_raw
    u16* C3    = alloc((size_t)BL_ * 4096);      // k_content | v
    u16* qbuf  = alloc((size_t)BL_ * QKS_);
    u16* kbuf  = alloc((size_t)BL_ * QKS_);
    u16* vt    = alloc((size_t)BL_ * NHHD_);
    u16* attn_o = alloc((size_t)BL_ * NHHD_);

    // 1. casts + fused weight transposes
    cast_bf16_kernel<<<(BL_ * H_ / 4 + 255) / 256, 256, 0, stream>>>(x, xb, BL_ * H_ / 4);
    cast_transpose<<<dim3(QR_ / 32, H_ / 32), 256, 0, stream>>>(wq_down, Wdn, H_, QR_, QR_);
    cast_transpose<<<dim3(KVR_ / 32, H_ / 32), 256, 0, stream>>>(wkv_down, Wdn + (size_t)768 * H_, H_, KVR_, KVR_);
    cast_transpose<<<dim3(128 / 32, H_ / 32), 256, 0, stream>>>(wk_rope, Wdn + (size_t)1280 * H_, H_, RD_, 128);
    cast_transpose<<<dim3(NHHD_ / 32, QR_ / 32), 256, 0, stream>>>(wq_up, Wupq, QR_, NHHD_, NHHD_);
    cast_transpose<<<dim3(1024 / 32, QR_ / 32), 256, 0, stream>>>(wq_rope, Wupq + (size_t)2048 * QR_, QR_, 1024, 1024);
    cast_transpose<<<dim3(NHHD_ / 32, KVR_ / 32), 256, 0, stream>>>(wk_up, Wupkv, KVR_, NHHD_, NHHD_);
    cast_transpose<<<dim3(NHHD_ / 32, KVR_ / 32), 256, 0, stream>>>(wv_up, Wupkv + (size_t)2048 * KVR_, KVR_, NHHD_, NHHD_);
    cast_transpose<<<dim3(NHHD_ / 32, H_ / 32), 256, 0, stream>>>(wo, Wo_t, NHHD_, H_, H_);

    // 2. fused projection GEMMs
    gemm_bt<0><<<dim3(1408 / 128, BL_ / 128), 256, 0, stream>>>(xb, H_, Wdn, C1, 1408, H_);
    gemm_bt<0><<<dim3(3072 / 128, BL_ / 128), 256, 0, stream>>>(C1, 1408, Wupq, C2, 3072, QR_);
    gemm_bt<0><<<dim3(4096 / 128, BL_ / 128), 256, 0, stream>>>(C1 + 768, 1408, Wupkv, C3, 4096, KVR_);

    // 3. assemble q, k, vt
    pack_content<<<BL_ * NHHD_ / 8 / 256, 256, 0, stream>>>(C2, 3072, qbuf);
    pack_content<<<BL_ * NHHD_ / 8 / 256, 256, 0, stream>>>(C3, 4096, kbuf);
    rope_q_kernel<<<BL_ * NH_ * 32 / 256, 256, 0, stream>>>(C2 + 2048, 3072, qbuf);
    rope_k_kernel<<<BL_ * 32 / 256, 256, 0, stream>>>(C1 + 1280, 1408, kbuf);
    transpose_v<<<dim3(NHHD_ / 64, L_ / 64, B_), 256, 0, stream>>>(C3 + 2048, 4096, vt);

    // 4. attention (paired qtiles, balanced)
    flash_attn<<<dim3(8, NH_, B_), 256, 0, stream>>>(qbuf, kbuf, vt, attn_o);

    // 5. output projection (fp32 out)
    gemm_bt<1><<<dim3(H_ / 128, BL_ / 128), 256, 0, stream>>>(attn_o, NHHD_, Wo_t, d_out, H_, NHHD_);
}